// Round 4
// baseline (392.686 us; speedup 1.0000x reference)
//
#include <hip/hip_runtime.h>
#include <float.h>

#define NV 4096
#define OSTRIDE 451
#define NT 512
#define PTS 512          // points scanned per thread, all stages
#define MSTR 9           // padded publish stride (floats) -> conflict-free

struct SMem {
    float dd[NT*MSTR];   // 18 KiB
    int   ii[NT*MSTR];   // 18 KiB
    int   idx[32*8];
    float w  [32*8];
};

// sorted top-8 insert; LEX=false: d2-only strict < (stable, earlier idx wins);
// LEX=true: (d2, idx) lexicographic (partition-order invariant merges).
template<bool LEX>
__device__ __forceinline__ void ins8(float (&dd)[8], int (&ii)[8], float cd, int cm) {
    bool b[7];
#pragma unroll
    for (int q = 0; q < 7; ++q)
        b[q] = LEX ? ((cd < dd[q]) || (cd == dd[q] && cm < ii[q])) : (cd < dd[q]);
#pragma unroll
    for (int q = 7; q >= 1; --q) {
        bool hi = (q == 7) ? true : b[q];
        dd[q] = b[q-1] ? dd[q-1] : (hi ? cd : dd[q]);
        ii[q] = b[q-1] ? ii[q-1] : (hi ? cm : ii[q]);
    }
    dd[0] = b[0] ? cd : dd[0];
    ii[0] = b[0] ? cm : ii[0];
}

// One KNN stage. Block owns VB vertices, P = NT/VB threads per vertex, each
// scanning PTS=512 consecutive points straight from global (L2-resident).
// Selection distance = direct form (p-v).(p-v): abs err ~ulp(d2), ~500x
// tighter than the reference's cancellation form -> matches f64 ordering.
template<int VB, int P, int M, int DF, int COFF, bool TR>
__device__ __forceinline__ void stage_body(
    const float* __restrict__ verts,
    const float* __restrict__ pc,     // [3*M]
    const float* __restrict__ feat,   // [DF*M]   (fallback gather)
    const float* __restrict__ featT,  // [M*DF]   (transposed gather)
    float* __restrict__ out,
    int vbase, SMem& sm)
{
    const int tid = threadIdx.x;
    const int v = tid & (VB - 1);
    const int c = tid / VB;
    const int n = vbase + v;
    const float vx = verts[n*3+0], vy = verts[n*3+1], vz = verts[n*3+2];

    float dd[8]; int ii[8];
#pragma unroll
    for (int q = 0; q < 8; ++q) { dd[q] = FLT_MAX; ii[q] = 0; }

    const int base = c * PTS;
    const float* __restrict__ px = pc + base;
    const float* __restrict__ py = pc + M + base;
    const float* __restrict__ pz = pc + 2*M + base;

#pragma unroll 2
    for (int j = 0; j < PTS; j += 4) {
        float4 X = *(const float4*)(px + j);
        float4 Y = *(const float4*)(py + j);
        float4 Z = *(const float4*)(pz + j);
        float dx0 = __fsub_rn(X.x, vx), dy0 = __fsub_rn(Y.x, vy), dz0 = __fsub_rn(Z.x, vz);
        float dx1 = __fsub_rn(X.y, vx), dy1 = __fsub_rn(Y.y, vy), dz1 = __fsub_rn(Z.y, vz);
        float dx2 = __fsub_rn(X.z, vx), dy2 = __fsub_rn(Y.z, vy), dz2 = __fsub_rn(Z.z, vz);
        float dx3 = __fsub_rn(X.w, vx), dy3 = __fsub_rn(Y.w, vy), dz3 = __fsub_rn(Z.w, vz);
        float d0 = __fmaf_rn(dz0, dz0, __fmaf_rn(dy0, dy0, __fmul_rn(dx0, dx0)));
        float d1 = __fmaf_rn(dz1, dz1, __fmaf_rn(dy1, dy1, __fmul_rn(dx1, dx1)));
        float d2 = __fmaf_rn(dz2, dz2, __fmaf_rn(dy2, dy2, __fmul_rn(dx2, dx2)));
        float d3 = __fmaf_rn(dz3, dz3, __fmaf_rn(dy3, dy3, __fmul_rn(dx3, dx3)));
        float mn = fminf(fminf(d0, d1), fminf(d2, d3));
        if (mn < dd[7]) {   // valid skip: dd[7] only shrinks
            if (d0 < dd[7]) ins8<false>(dd, ii, d0, base+j+0);
            if (d1 < dd[7]) ins8<false>(dd, ii, d1, base+j+1);
            if (d2 < dd[7]) ins8<false>(dd, ii, d2, base+j+2);
            if (d3 < dd[7]) ins8<false>(dd, ii, d3, base+j+3);
        }
    }

    // publish partial lists (stride MSTR=9 -> conflict-free writes)
#pragma unroll
    for (int q = 0; q < 8; ++q) { sm.dd[tid*MSTR+q] = dd[q]; sm.ii[tid*MSTR+q] = ii[q]; }
    __syncthreads();

    constexpr int G = P / 8;
    float md[8]; int mi[8];
    // level-1: threads c<G each merge the 8 sorted lists {c*8+r, v}
    if (c < G) {
#pragma unroll
        for (int q = 0; q < 8; ++q) { md[q] = FLT_MAX; mi[q] = 0x7fffffff; }
        for (int r = 0; r < 8; ++r) {
            const int pb = ((c*8 + r)*VB + v)*MSTR;
            for (int s = 0; s < 8; ++s) {
                float cd = sm.dd[pb+s]; int cm = sm.ii[pb+s];
                if (!((cd < md[7]) || (cd == md[7] && cm < mi[7]))) break; // sorted
                ins8<true>(md, mi, cd, cm);
            }
        }
    }
    __syncthreads();   // all level-1 reads done before republish
    if (c < G) {
#pragma unroll
        for (int q = 0; q < 8; ++q) { sm.dd[tid*MSTR+q] = md[q]; sm.ii[tid*MSTR+q] = mi[q]; }
    }
    __syncthreads();

    if (c == 0) {      // level-2: merge the G level-1 lists for vertex v
#pragma unroll
        for (int q = 0; q < 8; ++q) { md[q] = FLT_MAX; mi[q] = 0x7fffffff; }
        for (int r = 0; r < G; ++r) {
            const int pb = (r*VB + v)*MSTR;
            for (int s = 0; s < 8; ++s) {
                float cd = sm.dd[pb+s]; int cm = sm.ii[pb+s];
                if (!((cd < md[7]) || (cd == md[7] && cm < mi[7]))) break;
                ins8<true>(md, mi, cd, cm);
            }
        }
        // weights: reference recomputes dist2 from vec = nbr - vert,
        // numpy op order: round products, sequential add, no fma.
#pragma unroll
        for (int k = 0; k < 8; ++k) {
            int m = mi[k];
            float qx = pc[m], qy = pc[M+m], qz = pc[2*M+m];
            float dx = __fsub_rn(qx, vx), dy = __fsub_rn(qy, vy), dz = __fsub_rn(qz, vz);
            float dist2 = __fadd_rn(__fadd_rn(__fmul_rn(dx,dx), __fmul_rn(dy,dy)),
                                    __fmul_rn(dz,dz));
            sm.idx[v*8 + k] = m;
            sm.w  [v*8 + k] = __fdiv_rn(1.0f, __fadd_rn(1.0f, dist2));
        }
    }
    __syncthreads();

    // feature mean: out[n, COFF+f] = 0.125 * sum_k w_k * feat[idx_k, f]
    constexpr int TOT = VB * DF;
    for (int flat = tid; flat < TOT; flat += NT) {
        int v2 = flat / DF;
        int f  = flat & (DF - 1);
        float e[8];
#pragma unroll
        for (int k = 0; k < 8; ++k) {
            int m = sm.idx[v2*8 + k];
            float fv = TR ? featT[m*DF + f] : feat[f*M + m];
            e[k] = __fmul_rn(sm.w[v2*8 + k], fv);
        }
        float s = __fadd_rn(__fadd_rn(__fadd_rn(e[0],e[1]), __fadd_rn(e[2],e[3])),
                            __fadd_rn(__fadd_rn(e[4],e[5]), __fadd_rn(e[6],e[7])));
        out[(vbase + v2)*OSTRIDE + COFF + f] = __fmul_rn(0.125f, s);
    }
}

// fused transpose: feat [Df, M] -> featT [M, Df]; coalesced reads, 16B writes.
// Each of the 3 stages is exactly 524288 float4 elements = 2048 blocks.
__global__ __launch_bounds__(256)
void tr_kernel(const float* __restrict__ f1, const float* __restrict__ f2,
               const float* __restrict__ f3, float* __restrict__ ws)
{
    int b = blockIdx.x;
    const float* src; float* dst; int M, LOGM, DF;
    int g;
    if (b < 2048)      { src = f1; dst = ws;           M = 32768; LOGM = 15; DF = 64;  g = b*256 + threadIdx.x; }
    else if (b < 4096) { src = f2; dst = ws + 2097152; M = 16384; LOGM = 14; DF = 128; g = (b-2048)*256 + threadIdx.x; }
    else               { src = f3; dst = ws + 4194304; M = 8192;  LOGM = 13; DF = 256; g = (b-4096)*256 + threadIdx.x; }
    int m  = g & (M - 1);
    int f4 = g >> LOGM;           // f4 < DF/4
    float4 r;
    r.x = src[(4*f4+0)*M + m];
    r.y = src[(4*f4+1)*M + m];
    r.z = src[(4*f4+2)*M + m];
    r.w = src[(4*f4+3)*M + m];
    *(float4*)&dst[m*DF + 4*f4] = r;
}

template<bool TR>
__global__ __launch_bounds__(NT, 7)
void gp_kernel(const float* __restrict__ verts,
               const float* __restrict__ pc1, const float* __restrict__ f1,
               const float* __restrict__ pc2, const float* __restrict__ f2,
               const float* __restrict__ pc3, const float* __restrict__ f3,
               const float* __restrict__ ws,
               float* __restrict__ out)
{
    __shared__ SMem sm;
    int b = blockIdx.x;
    if (b < 512) {
        stage_body< 8, 64, 32768,  64,   3, TR>(verts, pc1, f1, ws,           out, b*8, sm);
    } else if (b < 768) {
        stage_body<16, 32, 16384, 128,  67, TR>(verts, pc2, f2, ws + 2097152, out, (b-512)*16, sm);
    } else if (b < 896) {
        stage_body<32, 16,  8192, 256, 195, TR>(verts, pc3, f3, ws + 4194304, out, (b-768)*32, sm);
    } else {
        for (int i = threadIdx.x; i < NV*3; i += NT)
            out[(i/3)*OSTRIDE + (i % 3)] = verts[i];
    }
}

extern "C" void kernel_launch(void* const* d_in, const int* in_sizes, int n_in,
                              void* d_out, int out_size, void* d_ws, size_t ws_size,
                              hipStream_t stream) {
    const float* verts = (const float*)d_in[0];
    // d_in[1] = pc0_coords: unused (reference discards stage 0)
    const float* pc1 = (const float*)d_in[2];
    const float* f1  = (const float*)d_in[3];
    const float* pc2 = (const float*)d_in[4];
    const float* f2  = (const float*)d_in[5];
    const float* pc3 = (const float*)d_in[6];
    const float* f3  = (const float*)d_in[7];
    float* out = (float*)d_out;
    float* ws  = (float*)d_ws;

    if (ws_size >= 6291456u * sizeof(float)) {
        tr_kernel<<<6144, 256, 0, stream>>>(f1, f2, f3, ws);
        gp_kernel<true><<<897, NT, 0, stream>>>(verts, pc1, f1, pc2, f2, pc3, f3, ws, out);
    } else {
        gp_kernel<false><<<897, NT, 0, stream>>>(verts, pc1, f1, pc2, f2, pc3, f3, ws, out);
    }
}

// Round 5
// 197.437 us; speedup vs baseline: 1.9889x; 1.9889x over previous
//
#include <hip/hip_runtime.h>
#include <float.h>

#define NV 4096
#define OSTRIDE 451
#define NT 256
typedef unsigned long long u64;

// key = (float-bits(d2) << 32) | idx. d2 >= 0 so float bits are monotone in
// value -> u64 compare == exact lexicographic (d2, idx) compare, which is
// precisely jax.lax.top_k's stable tie semantics.
__device__ __forceinline__ u64 packkey(float d, int idx) {
    return ((u64)__float_as_uint(d) << 32) | (u64)(unsigned)idx;
}

__device__ __forceinline__ void cswap(u64& a, u64& b) {
    bool c = a < b;
    u64 lo = c ? a : b;
    u64 hi = c ? b : a;
    a = lo; b = hi;
}

// sorted ascending insert of ck (caller guarantees ck < k[7]); drops k[7]
__device__ __forceinline__ void ins8(u64 (&k)[8], u64 ck) {
    bool b[7];
#pragma unroll
    for (int q = 0; q < 7; ++q) b[q] = ck < k[q];
#pragma unroll
    for (int q = 7; q >= 1; --q) {
        bool hi = (q == 7) ? true : b[q];
        k[q] = b[q-1] ? k[q-1] : (hi ? ck : k[q]);
    }
    k[0] = b[0] ? ck : k[0];
}

// One wave owns 4 consecutive vertices and scans all M points.
// Lanes scan one point each per 64-point batch (coalesced); the top-8 lists
// are wave-uniform. All branches are wave-uniform -> zero divergence tax.
// Selection distance = direct form (p-v).(p-v): abs err ~ulp(d2), ~500x
// tighter than the reference's cancellation form -> matches f64 ordering.
template<int M, int DF, int COFF, bool TR>
__device__ __forceinline__ void stage_wave(
    const float* __restrict__ verts,
    const float* __restrict__ pc,     // [3*M]
    const float* __restrict__ feat,   // [DF*M] (fallback gather)
    const float* __restrict__ featT,  // [M*DF] (transposed gather)
    float* __restrict__ out,
    int vbase)
{
    const int lane = threadIdx.x & 63;
    float vx[4], vy[4], vz[4];
#pragma unroll
    for (int u = 0; u < 4; ++u) {
        vx[u] = verts[(vbase+u)*3+0];
        vy[u] = verts[(vbase+u)*3+1];
        vz[u] = verts[(vbase+u)*3+2];
    }

    // seed: exact keys of points 0..7, sorted (Batcher 19-comparator network)
    u64 kk[4][8];
    {
        float sx[8], sy[8], sz[8];
#pragma unroll
        for (int q = 0; q < 8; ++q) { sx[q]=pc[q]; sy[q]=pc[M+q]; sz[q]=pc[2*M+q]; }
#pragma unroll
        for (int u = 0; u < 4; ++u) {
#pragma unroll
            for (int q = 0; q < 8; ++q) {
                float dx=__fsub_rn(sx[q],vx[u]), dy=__fsub_rn(sy[q],vy[u]), dz=__fsub_rn(sz[q],vz[u]);
                float d = __fmaf_rn(dz,dz,__fmaf_rn(dy,dy,__fmul_rn(dx,dx)));
                kk[u][q] = packkey(d, q);
            }
            cswap(kk[u][0],kk[u][1]); cswap(kk[u][2],kk[u][3]); cswap(kk[u][4],kk[u][5]); cswap(kk[u][6],kk[u][7]);
            cswap(kk[u][0],kk[u][2]); cswap(kk[u][1],kk[u][3]); cswap(kk[u][4],kk[u][6]); cswap(kk[u][5],kk[u][7]);
            cswap(kk[u][1],kk[u][2]); cswap(kk[u][5],kk[u][6]);
            cswap(kk[u][0],kk[u][4]); cswap(kk[u][1],kk[u][5]); cswap(kk[u][2],kk[u][6]); cswap(kk[u][3],kk[u][7]);
            cswap(kk[u][2],kk[u][4]); cswap(kk[u][3],kk[u][5]);
            cswap(kk[u][1],kk[u][2]); cswap(kk[u][3],kk[u][4]); cswap(kk[u][5],kk[u][6]);
        }
    }
    float T[4];
#pragma unroll
    for (int u = 0; u < 4; ++u) T[u] = __uint_as_float((unsigned)(kk[u][7] >> 32));

    const float* __restrict__ px = pc;
    const float* __restrict__ py = pc + M;
    const float* __restrict__ pz = pc + 2*M;

    // software-pipelined batch loop: prefetch next batch during compute
    float X = px[lane], Y = py[lane], Z = pz[lane];
    for (int ob = 0; ob < M; ob += 64) {
        int nb = (ob + 64 < M) ? (ob + 64) : 0;   // clamped; last prefetch dead
        float nX = px[nb+lane], nY = py[nb+lane], nZ = pz[nb+lane];
#pragma unroll
        for (int u = 0; u < 4; ++u) {
            float dx = __fsub_rn(X, vx[u]);
            float dy = __fsub_rn(Y, vy[u]);
            float dz = __fsub_rn(Z, vz[u]);
            float d  = __fmaf_rn(dz,dz,__fmaf_rn(dy,dy,__fmul_rn(dx,dx)));
            // strict < gate: candidates with d == d8th rank after (idx larger)
            u64 mask = __ballot(d < T[u]);
            while (mask) {                           // wave-uniform loop
                int l = __builtin_ctzll(mask);       // ascending lane = ascending idx
                mask &= mask - 1;
                float cd = __uint_as_float(__builtin_amdgcn_readlane(__float_as_uint(d), l));
                int cm = ob + l;
                if (cm >= 8) {                       // seed points already in list
                    u64 ck = packkey(cd, cm);
                    if (ck < kk[u][7]) {
                        ins8(kk[u], ck);
                        T[u] = __uint_as_float((unsigned)(kk[u][7] >> 32));
                        mask &= __ballot(d < T[u]);  // re-filter vs new threshold
                    }
                }
            }
        }
        X = nX; Y = nY; Z = nZ;
    }

    // weights (reference recomputes dist2 from vec = nbr - vert, numpy op
    // order: round products, sequential add, no fma) + feature mean.
#pragma unroll
    for (int u = 0; u < 4; ++u) {
        int   m8[8];
        float w8[8];
#pragma unroll
        for (int k = 0; k < 8; ++k) {
            int m = (int)(kk[u][k] & 0xFFFFFFFFu);
            m8[k] = m;
            float qx = pc[m], qy = pc[M+m], qz = pc[2*M+m];
            float dx = __fsub_rn(qx, vx[u]), dy = __fsub_rn(qy, vy[u]), dz = __fsub_rn(qz, vz[u]);
            float dist2 = __fadd_rn(__fadd_rn(__fmul_rn(dx,dx), __fmul_rn(dy,dy)),
                                    __fmul_rn(dz,dz));
            w8[k] = __fdiv_rn(1.0f, __fadd_rn(1.0f, dist2));
        }
        const int n = vbase + u;
        for (int f = lane; f < DF; f += 64) {
            float e[8];
#pragma unroll
            for (int k = 0; k < 8; ++k) {
                float fv = TR ? featT[m8[k]*DF + f] : feat[f*M + m8[k]];
                e[k] = __fmul_rn(w8[k], fv);
            }
            float s = __fadd_rn(__fadd_rn(__fadd_rn(e[0],e[1]), __fadd_rn(e[2],e[3])),
                                __fadd_rn(__fadd_rn(e[4],e[5]), __fadd_rn(e[6],e[7])));
            out[n*OSTRIDE + COFF + f] = __fmul_rn(0.125f, s);
        }
    }
}

// fused transpose: feat [Df, M] -> featT [M, Df]; coalesced reads, 16B writes.
__global__ __launch_bounds__(256)
void tr_kernel(const float* __restrict__ f1, const float* __restrict__ f2,
               const float* __restrict__ f3, float* __restrict__ ws)
{
    int b = blockIdx.x;
    const float* src; float* dst; int M, LOGM, DF;
    int g;
    if (b < 2048)      { src = f1; dst = ws;           M = 32768; LOGM = 15; DF = 64;  g = b*256 + threadIdx.x; }
    else if (b < 4096) { src = f2; dst = ws + 2097152; M = 16384; LOGM = 14; DF = 128; g = (b-2048)*256 + threadIdx.x; }
    else               { src = f3; dst = ws + 4194304; M = 8192;  LOGM = 13; DF = 256; g = (b-4096)*256 + threadIdx.x; }
    int m  = g & (M - 1);
    int f4 = g >> LOGM;           // f4 < DF/4
    float4 r;
    r.x = src[(4*f4+0)*M + m];
    r.y = src[(4*f4+1)*M + m];
    r.z = src[(4*f4+2)*M + m];
    r.w = src[(4*f4+3)*M + m];
    *(float4*)&dst[m*DF + 4*f4] = r;
}

template<bool TR>
__global__ __launch_bounds__(NT, 3)
void gp_kernel(const float* __restrict__ verts,
               const float* __restrict__ pc1, const float* __restrict__ f1,
               const float* __restrict__ pc2, const float* __restrict__ f2,
               const float* __restrict__ pc3, const float* __restrict__ f3,
               const float* __restrict__ ws,
               float* __restrict__ out)
{
    int b = blockIdx.x;
    int w = threadIdx.x >> 6;    // wave id in block (4 waves, 4 vertices each)
    if (b < 256) {
        stage_wave<32768,  64,   3, TR>(verts, pc1, f1, ws,           out, (b*4 + w)*4);
    } else if (b < 512) {
        stage_wave<16384, 128,  67, TR>(verts, pc2, f2, ws + 2097152, out, ((b-256)*4 + w)*4);
    } else if (b < 768) {
        stage_wave< 8192, 256, 195, TR>(verts, pc3, f3, ws + 4194304, out, ((b-512)*4 + w)*4);
    } else {
        for (int i = threadIdx.x; i < NV*3; i += NT)
            out[(i/3)*OSTRIDE + (i % 3)] = verts[i];
    }
}

extern "C" void kernel_launch(void* const* d_in, const int* in_sizes, int n_in,
                              void* d_out, int out_size, void* d_ws, size_t ws_size,
                              hipStream_t stream) {
    const float* verts = (const float*)d_in[0];
    // d_in[1] = pc0_coords: unused (reference discards stage 0)
    const float* pc1 = (const float*)d_in[2];
    const float* f1  = (const float*)d_in[3];
    const float* pc2 = (const float*)d_in[4];
    const float* f2  = (const float*)d_in[5];
    const float* pc3 = (const float*)d_in[6];
    const float* f3  = (const float*)d_in[7];
    float* out = (float*)d_out;
    float* ws  = (float*)d_ws;

    if (ws_size >= 6291456u * sizeof(float)) {
        tr_kernel<<<6144, 256, 0, stream>>>(f1, f2, f3, ws);
        gp_kernel<true><<<769, NT, 0, stream>>>(verts, pc1, f1, pc2, f2, pc3, f3, ws, out);
    } else {
        gp_kernel<false><<<769, NT, 0, stream>>>(verts, pc1, f1, pc2, f2, pc3, f3, ws, out);
    }
}